// Round 14
// baseline (310.504 us; speedup 1.0000x reference)
//
#include <hip/hip_runtime.h>
#include <hip/hip_bf16.h>
#include <hip/hip_fp16.h>

#define K 7
#define EPSF 1e-12f
#define LOG_INV_K (-1.9459101090932196f)   // log(1/7)
#define LOG7 1.9459101090932196f
#define LOG2_EPS (-39.8631371f)            // log2(1e-12)
#define LN2 0.69314718056f
#define INV_LN2 1.44269504f
#define SBN 256
#define SBSH 8
#define NSBMAX 1024
#define PB 256
#define CAP 8                              // live-list slots per lane

__device__ __forceinline__ float ldf(const void* p, size_t idx, int mode) {
    return mode ? ((const float*)p)[idx]
                : __bfloat162float(((const __hip_bfloat16*)p)[idx]);
}

__device__ __forceinline__ void load_psi(const void* W, float* psi, int mode) {
    if (threadIdx.x < K * K) {
        float w = ldf(W, threadIdx.x, mode);
        w = fminf(fmaxf(w, -10.f), 10.f);
        psi[threadIdx.x] = __expf(w);
    }
    __syncthreads();
}

__device__ __forceinline__ void bp_lin(const float* b, const float* psi, float* m) {
    float o[K], sum = 0.f;
#pragma unroll
    for (int j = 0; j < K; j++) {
        float acc = 0.f;
#pragma unroll
        for (int i = 0; i < K; i++) acc += b[i] * psi[i * K + j];
        o[j] = fmaxf(acc, EPSF);
        sum += o[j];
    }
    float inv = __fdividef(1.f, fmaxf(sum, EPSF));
#pragma unroll
    for (int j = 0; j < K; j++) m[j] = o[j] * inv;
}

__device__ __forceinline__ void acc_log_msg(const float* b, const float* psi, float* acc) {
    float m[K];
    bp_lin(b, psi, m);
#pragma unroll
    for (int j = 0; j < K; j++) acc[j] += __logf(m[j]);
}

// PD record: 16 B = {bf16 prior[7], u15 deg, u1 uniform-m1 flag}
__device__ __forceinline__ void dec_pd(uint4 w, float* p, int* degv, int* u1) {
    p[0] = __uint_as_float((w.x & 0xffffu) << 16);
    p[1] = __uint_as_float(w.x & 0xffff0000u);
    p[2] = __uint_as_float((w.y & 0xffffu) << 16);
    p[3] = __uint_as_float(w.y & 0xffff0000u);
    p[4] = __uint_as_float((w.z & 0xffffu) << 16);
    p[5] = __uint_as_float(w.z & 0xffff0000u);
    p[6] = __uint_as_float((w.w & 0xffffu) << 16);
    *degv = (int)((w.w >> 16) & 0x7fffu);
    *u1 = (int)(w.w >> 31);
}

__device__ __forceinline__ unsigned short f2h(float f) {
    __half h = __float2half_rn(f);
    return *reinterpret_cast<unsigned short*>(&h);
}
__device__ __forceinline__ float h2f(unsigned short u) {
    __half h;
    *reinterpret_cast<unsigned short*>(&h) = u;
    return __half2float(h);
}
// record: 7 fp16 mantissas + shared int16 exponent: value_i = m_i * 2^E
__device__ __forceinline__ uint4 pack7h(const float* m, int E) {
    uint4 r;
    r.x = (unsigned)f2h(m[0]) | ((unsigned)f2h(m[1]) << 16);
    r.y = (unsigned)f2h(m[2]) | ((unsigned)f2h(m[3]) << 16);
    r.z = (unsigned)f2h(m[4]) | ((unsigned)f2h(m[5]) << 16);
    r.w = (unsigned)f2h(m[6]) | ((unsigned)(E & 0xffff) << 16);
    return r;
}
__device__ __forceinline__ int unpack7h(uint4 w, float* m) {
    m[0] = h2f((unsigned short)(w.x & 0xffffu));
    m[1] = h2f((unsigned short)(w.x >> 16));
    m[2] = h2f((unsigned short)(w.y & 0xffffu));
    m[3] = h2f((unsigned short)(w.y >> 16));
    m[4] = h2f((unsigned short)(w.z & 0xffffu));
    m[5] = h2f((unsigned short)(w.z >> 16));
    m[6] = h2f((unsigned short)(w.w & 0xffffu));
    return (int)(short)(w.w >> 16);
}
__device__ __forceinline__ signed char clampE(int E) {
    return (signed char)(E < -120 ? -120 : (E > 120 ? 120 : E));
}

// sniff: dtype + psi structure; also zeros btot (fused memset)
__global__ void sniff11_kernel(const void* __restrict__ W, int* __restrict__ prm,
                               int* __restrict__ btot, int NSB) {
    if (blockIdx.x != 0) return;
    for (int i = threadIdx.x; i < NSB; i += 64) btot[i] = 0;
    if (threadIdx.x != 0) return;
    const unsigned int* Wraw = (const unsigned int*)W;
    int mode = ((Wraw[0] >> 16) != 0u) ? 1 : 0;
    float diag0 = 0.f, offd0 = 0.f;
    int structured = 1;
    for (int i = 0; i < K; i++)
        for (int j = 0; j < K; j++) {
            float w = ldf(W, i * K + j, mode);
            w = fminf(fmaxf(w, -10.f), 10.f);
            float e = __expf(w);
            if (i == 0 && j == 0) diag0 = e;
            if (i == 0 && j == 1) offd0 = e;
            if (i == j) { if (i > 0 && e != diag0) structured = 0; }
            else       { if (!(i == 0 && j == 1) && e != offd0) structured = 0; }
        }
    if (!(offd0 >= 0.2f) || !(diag0 >= offd0)) structured = 0;
    prm[0] = mode | (structured << 1);
    ((float*)prm)[1] = offd0;
    ((float*)prm)[2] = diag0;
}

// ===================== radix-partition CSR build =====================
__global__ void hist6_kernel(const int* __restrict__ dst, int* __restrict__ hist,
                             int* __restrict__ btot, int E, int EPB, int NSB) {
    __shared__ int h[NSBMAX];
    for (int i = threadIdx.x; i < NSB; i += 256) h[i] = 0;
    __syncthreads();
    int blk = blockIdx.x;
    int e0 = blk * EPB, e1 = min(e0 + EPB, E);
    for (int e = e0 + (int)threadIdx.x; e < e1; e += 256)
        atomicAdd(&h[dst[e] >> SBSH], 1);
    __syncthreads();
    for (int i = threadIdx.x; i < NSB; i += 256) {
        int c = h[i];
        hist[i * PB + blk] = c;
        if (c) atomicAdd(&btot[i], c);
    }
}

__global__ void bscan6_kernel(const int* __restrict__ btot, int* __restrict__ boff, int NSB) {
    __shared__ int s[1024];
    int t = threadIdx.x;
    int x = (t < NSB) ? btot[t] : 0;
    s[t] = x;
    __syncthreads();
    for (int o = 1; o < 1024; o <<= 1) {
        int y = (t >= o) ? s[t - o] : 0;
        __syncthreads();
        s[t] += y;
        __syncthreads();
    }
    if (t < NSB) boff[t] = s[t] - x;
    if (t == NSB - 1) boff[NSB] = s[t];
}

__global__ void sscan6_kernel(const int* __restrict__ hist, const int* __restrict__ boff,
                              int* __restrict__ woff) {
    __shared__ int s[PB];
    int b = blockIdx.x, t = threadIdx.x;
    int x = hist[b * PB + t];
    s[t] = x;
    __syncthreads();
    for (int o = 1; o < PB; o <<= 1) {
        int y = (t >= o) ? s[t - o] : 0;
        __syncthreads();
        s[t] += y;
        __syncthreads();
    }
    woff[b * PB + t] = boff[b] + s[t] - x;
}

__global__ void part6_kernel(const int* __restrict__ src, const int* __restrict__ dst,
                             const int* __restrict__ woff, unsigned int* __restrict__ coarse,
                             int E, int EPB, int NSB) {
    __shared__ int cur[NSBMAX];
    int blk = blockIdx.x;
    for (int i = threadIdx.x; i < NSB; i += 256) cur[i] = woff[i * PB + blk];
    __syncthreads();
    int e0 = blk * EPB, e1 = min(e0 + EPB, E);
    for (int e = e0 + (int)threadIdx.x; e < e1; e += 256) {
        int d = dst[e];
        int b = d >> SBSH;
        unsigned int pk = (unsigned int)src[e] | ((unsigned int)(d & (SBN - 1)) << 18);
        int pos = atomicAdd(&cur[b], 1);
        coarse[pos] = pk;
    }
}

// cfill + fused PD + M1h build (PD/M1h in their OWN buffers — not aliased with coarse)
__global__ void cfill13_kernel(const unsigned int* __restrict__ coarse,
                               const int* __restrict__ boff,
                               const void* __restrict__ prior, const void* __restrict__ W,
                               const int* __restrict__ prm,
                               int* __restrict__ cur, int* __restrict__ nbr,
                               uint4* __restrict__ PD, uint4* __restrict__ M1h, int n) {
    __shared__ int lcnt[SBN], lcur[SBN];
    __shared__ float psi[K * K];
    int b = blockIdx.x, t = threadIdx.x;
    int pm = prm[0];
    int mode = pm & 1, strq = (pm >> 1) & 1;
    float offd = ((const float*)prm)[1], diag = ((const float*)prm)[2];
    load_psi(W, psi, mode);
    for (int i = t; i < SBN; i += 256) lcnt[i] = 0;
    __syncthreads();
    int s0 = boff[b], s1 = boff[b + 1];
    for (int i = s0 + t; i < s1; i += 256)
        atomicAdd(&lcnt[coarse[i] >> 18], 1);
    __syncthreads();
    if (t == 0) {
        int a = s0;
        for (int l = 0; l < SBN; l++) { lcur[l] = a; a += lcnt[l]; }
    }
    __syncthreads();
    int v0 = b << SBSH;
    for (int i = t; i < SBN; i += 256) {
        int v = v0 + i;
        if (v >= n) continue;
        int degv = lcnt[i];
        cur[v] = lcur[i] + degv;
        unsigned int pb[K];
        float p[K];
        if (mode == 0) {
            const unsigned short* pr = (const unsigned short*)prior;
#pragma unroll
            for (int j = 0; j < K; j++) {
                pb[j] = pr[(size_t)v * K + j];
                p[j] = __uint_as_float(pb[j] << 16);
            }
        } else {
            const float* pr = (const float*)prior;
#pragma unroll
            for (int j = 0; j < K; j++) {
                p[j] = pr[(size_t)v * K + j];
                __hip_bfloat16 hh = __float2bfloat16(p[j]);
                pb[j] = *(unsigned short*)&hh;
            }
        }
        float es = __expf((float)(degv - 1) * LOG_INV_K);
        float mx = p[0];
#pragma unroll
        for (int j = 1; j < K; j++) mx = fmaxf(mx, p[j]);
        unsigned int u1 = (mx * es <= EPSF) ? 1u : 0u;
        int dcap = degv > 0x7fff ? 0x7fff : degv;
        uint4 w;
        w.x = pb[0] | (pb[1] << 16);
        w.y = pb[2] | (pb[3] << 16);
        w.z = pb[4] | (pb[5] << 16);
        w.w = pb[6] | (((unsigned int)dcap) << 16) | (u1 << 31);
        PD[v] = w;
        // fused M1h: 7*m1(v); u1 nodes -> exactly 1.0 each
        float bb[K], S = 0.f;
#pragma unroll
        for (int j = 0; j < K; j++) { bb[j] = fmaxf(p[j] * es, EPSF); S += bb[j]; }
        float m1n[K];
        if (strq) {
            float cb = diag - offd, norm = 6.f * offd + diag;
            float sc = __fdividef(7.f, S * norm);
#pragma unroll
            for (int j = 0; j < K; j++) m1n[j] = (offd * S + cb * bb[j]) * sc;
        } else {
            float m1[K];
            bp_lin(bb, psi, m1);
#pragma unroll
            for (int j = 0; j < K; j++) m1n[j] = 7.f * m1[j];
        }
        M1h[v] = pack7h(m1n, 0);
    }
    __syncthreads();
    for (int i = s0 + t; i < s1; i += 256) {
        unsigned int w = coarse[i];
        int pos = atomicAdd(&lcur[w >> 18], 1);
        nbr[pos] = (int)(w & 0x3FFFFu);
    }
}

// ===================== node passes (n2: 4 thr/node; n3/n4: 8 thr/node) ==========
__global__ void n2v12_kernel(const int* __restrict__ cur, const int* __restrict__ nbr,
                             const uint4* __restrict__ M1h, const uint4* __restrict__ PD,
                             const int* __restrict__ prm, uint4* __restrict__ LP1,
                             signed char* __restrict__ E1x, int n) {
    int t = blockIdx.x * blockDim.x + threadIdx.x;
    int v = t >> 2, qi = t & 3;
    if (v >= n) return;
    int start = v ? cur[v - 1] : 0, end = cur[v];
    int len = end - start;
    int lo = start + ((len * qi) >> 2), hi = start + ((len * (qi + 1)) >> 2);
    float acc[K] = {1.f, 1.f, 1.f, 1.f, 1.f, 1.f, 1.f};
    int e = lo;
    for (; e + 3 < hi; e += 4) {
        int u0 = nbr[e], u1 = nbr[e + 1], u2 = nbr[e + 2], u3 = nbr[e + 3];
        uint4 w0 = M1h[u0], w1 = M1h[u1], w2 = M1h[u2], w3 = M1h[u3];
        float a[K], b[K], c[K], d[K];
        unpack7h(w0, a); unpack7h(w1, b); unpack7h(w2, c); unpack7h(w3, d);
#pragma unroll
        for (int i = 0; i < K; i++) acc[i] *= (a[i] * b[i]) * (c[i] * d[i]);
    }
    for (; e < hi; e++) {
        float a[K];
        unpack7h(M1h[nbr[e]], a);
#pragma unroll
        for (int i = 0; i < K; i++) acc[i] *= fmaxf(a[i], 1e-30f);
    }
#pragma unroll
    for (int i = 0; i < K; i++) {
        acc[i] *= __shfl_xor(acc[i], 1, 64);
        acc[i] *= __shfl_xor(acc[i], 2, 64);
    }
    if (qi) return;
    float pv[K]; int dv, u1v;
    dec_pd(PD[v], pv, &dv, &u1v);
    float le[K], mx = -1e30f;
    float corr = (float)len * LOG7;
#pragma unroll
    for (int i = 0; i < K; i++) {
        le[i] = __logf(fmaxf(pv[i] * acc[i], 1e-37f)) - corr;
        mx = fmaxf(mx, le[i]);
    }
    int E1 = (int)ceilf(mx * INV_LN2);
    float fm[K];
#pragma unroll
    for (int i = 0; i < K; i++) fm[i] = __expf(le[i] - (float)E1 * LN2);
    LP1[v] = pack7h(fm, E1);
    E1x[v] = clampE(E1);
}

__global__ void n3v14_kernel(const int* __restrict__ cur, const int* __restrict__ nbr,
                             const uint4* __restrict__ PD, const uint4* __restrict__ LP1,
                             const signed char* __restrict__ E1x,
                             const void* __restrict__ W, const int* __restrict__ prm,
                             uint4* __restrict__ Q2h, signed char* __restrict__ E2x, int n) {
    __shared__ float psi[K * K];
    __shared__ int lively[256 * CAP];   // [depth*256 + lane] -> conflict-free
    int pm = prm[0];
    int mode = pm & 1, strq = (pm >> 1) & 1;
    float offd = ((const float*)prm)[1], diag = ((const float*)prm)[2];
    load_psi(W, psi, mode);
    int t = blockIdx.x * blockDim.x + threadIdx.x;
    int v = t >> 3, qi = t & 7;
    if (v >= n) return;
    int start = v ? cur[v - 1] : 0, end = cur[v];
    int len = end - start;
    int lo = start + ((len * qi) >> 3), hi = start + ((len * (qi + 1)) >> 3);
    float cb = diag - offd, norm = 6.f * offd + diag;
    float pv[K]; int dv, u1v;
    dec_pd(PD[v], pv, &dv, &u1v);
    float rm1v[K];
    if (strq && u1v) {
#pragma unroll
        for (int i = 0; i < K; i++) rm1v[i] = 7.f;
    } else {
        float es = __expf((float)(dv - 1) * LOG_INV_K);
        float b1[K], S1 = 0.f;
#pragma unroll
        for (int i = 0; i < K; i++) { b1[i] = fmaxf(pv[i] * es, EPSF); S1 += b1[i]; }
        if (strq) {
            float inv = __fdividef(1.f, S1 * norm);
#pragma unroll
            for (int i = 0; i < K; i++)
                rm1v[i] = __fdividef(1.f, (offd * S1 + cb * b1[i]) * inv);
        } else {
            float m1[K];
            bp_lin(b1, psi, m1);
#pragma unroll
            for (int i = 0; i < K; i++) rm1v[i] = __fdividef(1.f, m1[i]);
        }
    }
    float acc[K];
    int cn = 0;
    if (strq) {
        float F = __fdividef(norm, offd) * 1.01f;
        int Ethr = (int)floorf(LOG2_EPS - log2f(F));
#pragma unroll
        for (int i = 0; i < K; i++) acc[i] = 1.f;
        auto proc = [&](uint4 q) {
            float m[K];
            int E = unpack7h(q, m);
            float b[K], S = 0.f;
#pragma unroll
            for (int i = 0; i < K; i++) {
                b[i] = fmaxf(ldexpf(m[i] * rm1v[i], E), EPSF);
                S += b[i];
            }
            float crS = __fdividef(cb, S);
#pragma unroll
            for (int i = 0; i < K; i++) acc[i] *= fmaf(crS, b[i], offd);
            cn++;
        };
        int lane = (int)threadIdx.x;
        int cnt = 0;
        auto consider = [&](int u, int Eu) {
            if (Eu > Ethr) {
                if (cnt < CAP) lively[cnt++ * 256 + lane] = u;
                else proc(LP1[u]);
            }
        };
        int e = lo;
        for (; e + 3 < hi; e += 4) {
            int u0 = nbr[e], u1 = nbr[e + 1], u2 = nbr[e + 2], u3 = nbr[e + 3];
            int a0 = E1x[u0], a1 = E1x[u1], a2 = E1x[u2], a3 = E1x[u3];
            consider(u0, a0); consider(u1, a1); consider(u2, a2); consider(u3, a3);
        }
        for (; e < hi; e++) { int u = nbr[e]; consider(u, (int)E1x[u]); }
        for (int j = 0; j < cnt; j++) proc(LP1[lively[j * 256 + lane]]);
#pragma unroll
        for (int i = 0; i < K; i++) {
            acc[i] *= __shfl_xor(acc[i], 1, 64);
            acc[i] *= __shfl_xor(acc[i], 2, 64);
            acc[i] *= __shfl_xor(acc[i], 4, 64);
        }
    } else {
#pragma unroll
        for (int i = 0; i < K; i++) acc[i] = 0.f;
        for (int e = lo; e < hi; e++) {
            float m[K];
            int E = unpack7h(LP1[nbr[e]], m);
            float b[K];
#pragma unroll
            for (int i = 0; i < K; i++)
                b[i] = fmaxf(ldexpf(m[i] * rm1v[i], E), EPSF);
            acc_log_msg(b, psi, acc);
        }
#pragma unroll
        for (int i = 0; i < K; i++) {
            acc[i] += __shfl_xor(acc[i], 1, 64);
            acc[i] += __shfl_xor(acc[i], 2, 64);
            acc[i] += __shfl_xor(acc[i], 4, 64);
        }
    }
    cn += __shfl_xor(cn, 1, 64);
    cn += __shfl_xor(cn, 2, 64);
    cn += __shfl_xor(cn, 4, 64);
    if (qi) return;
    float le2[K], mx = -1e30f;
    if (strq) {
        float corr = (float)cn * __logf(norm) + (float)(len - cn) * LOG7;
#pragma unroll
        for (int i = 0; i < K; i++) {
            le2[i] = __logf(fmaxf(pv[i] * acc[i], 1e-37f)) - corr;
            mx = fmaxf(mx, le2[i]);
        }
    } else {
#pragma unroll
        for (int i = 0; i < K; i++) {
            le2[i] = __logf(fmaxf(pv[i], 1e-37f)) + acc[i];
            mx = fmaxf(mx, le2[i]);
        }
    }
    int E2 = (int)ceilf(mx * INV_LN2);
    float fm[K];
#pragma unroll
    for (int i = 0; i < K; i++) fm[i] = __expf(le2[i] - (float)E2 * LN2);
    Q2h[v] = pack7h(fm, E2);
    E2x[v] = clampE(E2);
}

__global__ void n4v14_kernel(const int* __restrict__ cur, const int* __restrict__ nbr,
                             const uint4* __restrict__ M1h, const uint4* __restrict__ Q2h,
                             const signed char* __restrict__ E2x,
                             const uint4* __restrict__ LP1, const void* __restrict__ prior,
                             const void* __restrict__ W, const int* __restrict__ prm,
                             void* __restrict__ out, int n) {
    __shared__ float psi[K * K];
    __shared__ int lively[256 * CAP];
    int pm = prm[0];
    int mode = pm & 1, strq = (pm >> 1) & 1;
    float offd = ((const float*)prm)[1], diag = ((const float*)prm)[2];
    load_psi(W, psi, mode);
    int t = blockIdx.x * blockDim.x + threadIdx.x;
    int v = t >> 3, qi = t & 7;
    if (v >= n) return;
    int start = v ? cur[v - 1] : 0, end = cur[v];
    int len = end - start;
    int lo = start + ((len * qi) >> 3), hi = start + ((len * (qi + 1)) >> 3);
    float cb = diag - offd, norm = 6.f * offd + diag;
    float e1v[K];
    {
        float m[K];
        int E1 = unpack7h(LP1[v], m);
#pragma unroll
        for (int i = 0; i < K; i++) e1v[i] = ldexpf(m[i], E1);
    }
    float acc[K];
    int cn = 0;
    if (strq) {
        float mx1 = e1v[0];
#pragma unroll
        for (int i = 1; i < K; i++) mx1 = fmaxf(mx1, e1v[i]);
        float F = __fdividef(norm, offd) * 1.01f;
        int m2u = (F * mx1 <= EPSF);
        int Ethr = (int)floorf(LOG2_EPS - log2f(F));
#pragma unroll
        for (int i = 0; i < K; i++) acc[i] = 1.f;
        auto proc2u = [&](int u) {
            float m[K];
            int E2 = unpack7h(Q2h[u], m);
            float b3[K], S = 0.f;
#pragma unroll
            for (int i = 0; i < K; i++) {
                b3[i] = fmaxf(ldexpf(m[i] * 7.f, E2), EPSF);
                S += b3[i];
            }
            float crS = __fdividef(cb, S);
#pragma unroll
            for (int i = 0; i < K; i++) acc[i] *= fmaf(crS, b3[i], offd);
            cn++;
        };
        auto procGen = [&](int u) {
            float m[K];
            int E2 = unpack7h(Q2h[u], m);
            float tt[K];
            unpack7h(M1h[u], tt);
            float b2[K], S2 = 0.f;
#pragma unroll
            for (int i = 0; i < K; i++) {
                b2[i] = fmaxf(e1v[i] * __fdividef(7.f, tt[i]), EPSF);
                S2 += b2[i];
            }
            float inv2 = __fdividef(1.f, S2 * norm);
            float b3[K], S3 = 0.f;
#pragma unroll
            for (int i = 0; i < K; i++) {
                float m2v = (offd * S2 + cb * b2[i]) * inv2;
                float e2 = ldexpf(m[i], E2);
                b3[i] = fmaxf(__fdividef(e2, m2v), EPSF);
                S3 += b3[i];
            }
            float crS3 = __fdividef(cb, S3);
#pragma unroll
            for (int i = 0; i < K; i++) acc[i] *= fmaf(crS3, b3[i], offd);
            cn++;
        };
        int lane = (int)threadIdx.x;
        int cnt = 0;
        auto consider = [&](int u, int Eu) {
            if (Eu > Ethr) {
                if (cnt < CAP) lively[cnt++ * 256 + lane] = u;
                else { if (m2u) proc2u(u); else procGen(u); }
            }
        };
        int e = lo;
        for (; e + 3 < hi; e += 4) {
            int u0 = nbr[e], u1 = nbr[e + 1], u2 = nbr[e + 2], u3 = nbr[e + 3];
            int a0 = E2x[u0], a1 = E2x[u1], a2 = E2x[u2], a3 = E2x[u3];
            consider(u0, a0); consider(u1, a1); consider(u2, a2); consider(u3, a3);
        }
        for (; e < hi; e++) { int u = nbr[e]; consider(u, (int)E2x[u]); }
        if (m2u) { for (int j = 0; j < cnt; j++) proc2u(lively[j * 256 + lane]); }
        else     { for (int j = 0; j < cnt; j++) procGen(lively[j * 256 + lane]); }
#pragma unroll
        for (int i = 0; i < K; i++) {
            acc[i] *= __shfl_xor(acc[i], 1, 64);
            acc[i] *= __shfl_xor(acc[i], 2, 64);
            acc[i] *= __shfl_xor(acc[i], 4, 64);
        }
    } else {
#pragma unroll
        for (int i = 0; i < K; i++) acc[i] = 0.f;
        for (int e = lo; e < hi; e++) {
            int u = nbr[e];
            uint4 q = Q2h[u];
            float m[K];
            int E2 = unpack7h(q, m);
            float tt[K];
            unpack7h(M1h[u], tt);
            float b2[K];
#pragma unroll
            for (int i = 0; i < K; i++)
                b2[i] = fmaxf(e1v[i] * __fdividef(7.f, fmaxf(tt[i], 1e-30f)), EPSF);
            float m2[K];
            bp_lin(b2, psi, m2);
            float b3[K];
#pragma unroll
            for (int i = 0; i < K; i++) {
                float e2 = ldexpf(m[i], E2);
                b3[i] = fmaxf(__fdividef(e2, m2[i]), EPSF);
            }
            acc_log_msg(b3, psi, acc);
        }
#pragma unroll
        for (int i = 0; i < K; i++) {
            acc[i] += __shfl_xor(acc[i], 1, 64);
            acc[i] += __shfl_xor(acc[i], 2, 64);
            acc[i] += __shfl_xor(acc[i], 4, 64);
        }
    }
    cn += __shfl_xor(cn, 1, 64);
    cn += __shfl_xor(cn, 2, 64);
    cn += __shfl_xor(cn, 4, 64);
    if (qi) return;
    float bb[K], sum = 0.f;
    if (strq) {
        float corr = (float)cn * __logf(norm) + (float)(len - cn) * LOG7;
#pragma unroll
        for (int i = 0; i < K; i++) {
            float p = ldf(prior, (size_t)v * K + i, mode);
            bb[i] = fmaxf(__expf(__logf(fmaxf(p * acc[i], 1e-37f)) - corr), EPSF);
            sum += bb[i];
        }
    } else {
#pragma unroll
        for (int i = 0; i < K; i++) {
            float p = ldf(prior, (size_t)v * K + i, mode);
            bb[i] = fmaxf(p * __expf(acc[i]), EPSF);
            sum += bb[i];
        }
    }
    float inv = __fdividef(1.f, fmaxf(sum, EPSF));
#pragma unroll
    for (int i = 0; i < K; i++) {
        float val = bb[i] * inv;
        if (mode) ((float*)out)[(size_t)v * K + i] = val;
        else ((__hip_bfloat16*)out)[(size_t)v * K + i] = __float2bfloat16(val);
    }
}

// ===================== fallback: round-2 atomic path (proven) =====================
__device__ __forceinline__ void bp_msg(const float* b, const float* psi, float* lm) {
    float m[K];
    bp_lin(b, psi, m);
#pragma unroll
    for (int j = 0; j < K; j++) lm[j] = __logf(m[j]);
}
__device__ __forceinline__ void msg1(const void* prior, int node, int degv, int mode,
                                     const float* psi, float* lm) {
    float es = __expf((float)(degv - 1) * LOG_INV_K);
    float b[K];
#pragma unroll
    for (int i = 0; i < K; i++)
        b[i] = fmaxf(ldf(prior, (size_t)node * K + i, mode) * es, EPSF);
    bp_msg(b, psi, lm);
}
__device__ __forceinline__ void msgF(const void* prior, int node,
                                     const float* __restrict__ logP,
                                     const float* lmrev, int mode,
                                     const float* psi, float* lm) {
    float b[K];
#pragma unroll
    for (int i = 0; i < K; i++)
        b[i] = fmaxf(ldf(prior, (size_t)node * K + i, mode) *
                     __expf(logP[(size_t)node * K + i] - lmrev[i]), EPSF);
    bp_msg(b, psi, lm);
}
__global__ void deg_kernel(const int* __restrict__ su, const int* __restrict__ du,
                           int* __restrict__ deg, int Eu) {
    int u = blockIdx.x * blockDim.x + threadIdx.x;
    if (u >= Eu) return;
    atomicAdd(&deg[su[u]], 1);
    atomicAdd(&deg[du[u]], 1);
}
__global__ void pass1_kernel(const int* __restrict__ su, const int* __restrict__ du,
                             const int* __restrict__ deg, const void* __restrict__ prior,
                             const void* __restrict__ W, const int* __restrict__ prm,
                             float* __restrict__ logP1, int Eu) {
    __shared__ float psi[K * K];
    int mode = prm[0] & 1;
    load_psi(W, psi, mode);
    int u = blockIdx.x * blockDim.x + threadIdx.x;
    if (u >= Eu) return;
    int s = su[u], d = du[u];
    float lm[K];
    msg1(prior, s, deg[s], mode, psi, lm);
#pragma unroll
    for (int j = 0; j < K; j++) atomicAdd(&logP1[(size_t)d * K + j], lm[j]);
    msg1(prior, d, deg[d], mode, psi, lm);
#pragma unroll
    for (int j = 0; j < K; j++) atomicAdd(&logP1[(size_t)s * K + j], lm[j]);
}
__global__ void pass2_kernel(const int* __restrict__ su, const int* __restrict__ du,
                             const int* __restrict__ deg, const void* __restrict__ prior,
                             const void* __restrict__ W, const int* __restrict__ prm,
                             const float* __restrict__ logP1, float* __restrict__ logP2, int Eu) {
    __shared__ float psi[K * K];
    int mode = prm[0] & 1;
    load_psi(W, psi, mode);
    int u = blockIdx.x * blockDim.x + threadIdx.x;
    if (u >= Eu) return;
    int s = su[u], d = du[u];
    float lm1sd[K], lm1ds[K], lm[K];
    msg1(prior, s, deg[s], mode, psi, lm1sd);
    msg1(prior, d, deg[d], mode, psi, lm1ds);
    msgF(prior, s, logP1, lm1ds, mode, psi, lm);
#pragma unroll
    for (int j = 0; j < K; j++) atomicAdd(&logP2[(size_t)d * K + j], lm[j]);
    msgF(prior, d, logP1, lm1sd, mode, psi, lm);
#pragma unroll
    for (int j = 0; j < K; j++) atomicAdd(&logP2[(size_t)s * K + j], lm[j]);
}
__global__ void pass3_kernel(const int* __restrict__ su, const int* __restrict__ du,
                             const int* __restrict__ deg, const void* __restrict__ prior,
                             const void* __restrict__ W, const int* __restrict__ prm,
                             const float* __restrict__ logP1, const float* __restrict__ logP2,
                             float* __restrict__ logP3, int Eu) {
    __shared__ float psi[K * K];
    int mode = prm[0] & 1;
    load_psi(W, psi, mode);
    int u = blockIdx.x * blockDim.x + threadIdx.x;
    if (u >= Eu) return;
    int s = su[u], d = du[u];
    float lm1sd[K], lm1ds[K], lm2sd[K], lm2ds[K], lm[K];
    msg1(prior, s, deg[s], mode, psi, lm1sd);
    msg1(prior, d, deg[d], mode, psi, lm1ds);
    msgF(prior, s, logP1, lm1ds, mode, psi, lm2sd);
    msgF(prior, d, logP1, lm1sd, mode, psi, lm2ds);
    msgF(prior, s, logP2, lm2ds, mode, psi, lm);
#pragma unroll
    for (int j = 0; j < K; j++) atomicAdd(&logP3[(size_t)d * K + j], lm[j]);
    msgF(prior, d, logP2, lm2sd, mode, psi, lm);
#pragma unroll
    for (int j = 0; j < K; j++) atomicAdd(&logP3[(size_t)s * K + j], lm[j]);
}
__global__ void belief_kernel(const float* __restrict__ logP3, const void* __restrict__ prior,
                              const int* __restrict__ prm, void* __restrict__ out, int n) {
    int v = blockIdx.x * blockDim.x + threadIdx.x;
    if (v >= n) return;
    int mode = prm[0] & 1;
    float b[K], sum = 0.f;
#pragma unroll
    for (int j = 0; j < K; j++) {
        b[j] = fmaxf(ldf(prior, (size_t)v * K + j, mode) * __expf(logP3[(size_t)v * K + j]), EPSF);
        sum += b[j];
    }
    float inv = __fdividef(1.f, fmaxf(sum, EPSF));
#pragma unroll
    for (int j = 0; j < K; j++) {
        float val = b[j] * inv;
        if (mode) ((float*)out)[(size_t)v * K + j] = val;
        else ((__hip_bfloat16*)out)[(size_t)v * K + j] = __float2bfloat16(val);
    }
}

extern "C" void kernel_launch(void* const* d_in, const int* in_sizes, int n_in,
                              void* d_out, int out_size, void* d_ws, size_t ws_size,
                              hipStream_t stream) {
    const void* prior = d_in[0];
    const void* W     = d_in[1];
    const int* src = (const int*)d_in[2];
    const int* dst = (const int*)d_in[3];

    int n  = in_sizes[0] / K;
    int E  = in_sizes[2];
    int Eu = E / 2;

    const int B = 256;
    int gn  = (n + B - 1) / B;
    int gn4 = (4 * n + B - 1) / B;
    int gn8 = (8 * n + B - 1) / B;
    int ge  = (Eu + B - 1) / B;

    int NSB = (n + SBN - 1) >> SBSH;
    int EPB = (E + PB - 1) / PB;

    char* ws = (char*)d_ws;
    size_t off = 0;
    auto alloc = [&](size_t bytes) { size_t o = off; off = (off + bytes + 127) & ~(size_t)127; return o; };

    // v14 layout: nbr | X (coarse E*4; after build: LP1@0, Q2h@n*16) | PD n*16 |
    //             M1h n*16 | E1x n | E2x n | cur | hist | woff | boff | btot | prm
    size_t xsz = (size_t)E * 4;
    if ((size_t)n * 32 > xsz) xsz = (size_t)n * 32;
    size_t o_nbr  = alloc((size_t)E * 4);
    size_t o_X    = alloc(xsz);
    size_t o_PD   = alloc((size_t)n * 16);
    size_t o_M1h  = alloc((size_t)n * 16);
    size_t o_E1x  = alloc((size_t)n);
    size_t o_E2x  = alloc((size_t)n);
    size_t o_cur  = alloc((size_t)n * 4);
    size_t o_hist = alloc((size_t)NSB * PB * 4);
    size_t o_woff = alloc((size_t)NSB * PB * 4);
    size_t o_boff = alloc((size_t)(NSB + 1) * 4);
    size_t o_btot = alloc((size_t)NSB * 4);
    size_t o_prm  = alloc(64);
    size_t need_v14 = off;

    bool v14_ok = (ws_size >= need_v14) && (n <= (1 << 18)) && (NSB <= NSBMAX) && (NSB >= 1);

    if (v14_ok) {
        int*   nbr    = (int*)(ws + o_nbr);
        unsigned int* coarse = (unsigned int*)(ws + o_X);   // dead after cfill13
        uint4* LP1    = (uint4*)(ws + o_X);                 // X reuse after build
        uint4* Q2h    = (uint4*)(ws + o_X + (size_t)n * 16);
        uint4* PD     = (uint4*)(ws + o_PD);
        uint4* M1h    = (uint4*)(ws + o_M1h);
        signed char* E1x = (signed char*)(ws + o_E1x);
        signed char* E2x = (signed char*)(ws + o_E2x);
        int*   cur    = (int*)(ws + o_cur);
        int*   hist   = (int*)(ws + o_hist);
        int*   woff   = (int*)(ws + o_woff);
        int*   boff   = (int*)(ws + o_boff);
        int*   btot   = (int*)(ws + o_btot);
        int*   prm    = (int*)(ws + o_prm);

        sniff11_kernel<<<1, 64, 0, stream>>>(W, prm, btot, NSB);
        hist6_kernel<<<PB, B, 0, stream>>>(dst, hist, btot, E, EPB, NSB);
        bscan6_kernel<<<1, 1024, 0, stream>>>(btot, boff, NSB);
        sscan6_kernel<<<NSB, PB, 0, stream>>>(hist, boff, woff);
        part6_kernel<<<PB, B, 0, stream>>>(src, dst, woff, coarse, E, EPB, NSB);
        cfill13_kernel<<<NSB, B, 0, stream>>>(coarse, boff, prior, W, prm, cur, nbr,
                                              PD, M1h, n);
        n2v12_kernel<<<gn4, B, 0, stream>>>(cur, nbr, M1h, PD, prm, LP1, E1x, n);
        n3v14_kernel<<<gn8, B, 0, stream>>>(cur, nbr, PD, LP1, E1x, W, prm, Q2h, E2x, n);
        n4v14_kernel<<<gn8, B, 0, stream>>>(cur, nbr, M1h, Q2h, E2x, LP1, prior, W, prm,
                                            d_out, n);
        return;
    }

    // fallback: round-2 atomic path (17.6 MB)
    {
        float* logP1 = (float*)d_ws;
        float* logP2 = logP1 + (size_t)n * K;
        float* logP3 = logP2 + (size_t)n * K;
        int*   deg   = (int*)(logP3 + (size_t)n * K);
        int*   prm   = deg + n;
        int*   btot  = prm + 8;
        sniff11_kernel<<<1, 64, 0, stream>>>(W, prm, btot, 0);
        hipMemsetAsync(d_ws, 0, ((size_t)3 * n * K + n) * sizeof(float), stream);
        deg_kernel<<<ge, B, 0, stream>>>(src, dst, deg, Eu);
        pass1_kernel<<<ge, B, 0, stream>>>(src, dst, deg, prior, W, prm, logP1, Eu);
        pass2_kernel<<<ge, B, 0, stream>>>(src, dst, deg, prior, W, prm, logP1, logP2, Eu);
        pass3_kernel<<<ge, B, 0, stream>>>(src, dst, deg, prior, W, prm, logP1, logP2, logP3, Eu);
        belief_kernel<<<gn, B, 0, stream>>>(logP3, prior, prm, d_out, n);
    }
}

// Round 15
// 291.336 us; speedup vs baseline: 1.0658x; 1.0658x over previous
//
#include <hip/hip_runtime.h>
#include <hip/hip_bf16.h>
#include <hip/hip_fp16.h>

#define K 7
#define EPSF 1e-12f
#define LOG_INV_K (-1.9459101090932196f)   // log(1/7)
#define LOG7 1.9459101090932196f
#define LOG2_EPS (-39.8631371f)            // log2(1e-12)
#define LN2 0.69314718056f
#define INV_LN2 1.44269504f
#define SBN 512
#define SBSH 9
#define NSBMAX 768
#define PB 256
#define CAP 8                              // live-list slots per lane

__device__ __forceinline__ float ldf(const void* p, size_t idx, int mode) {
    return mode ? ((const float*)p)[idx]
                : __bfloat162float(((const __hip_bfloat16*)p)[idx]);
}

__device__ __forceinline__ void load_psi(const void* W, float* psi, int mode) {
    if (threadIdx.x < K * K) {
        float w = ldf(W, threadIdx.x, mode);
        w = fminf(fmaxf(w, -10.f), 10.f);
        psi[threadIdx.x] = __expf(w);
    }
    __syncthreads();
}

__device__ __forceinline__ void bp_lin(const float* b, const float* psi, float* m) {
    float o[K], sum = 0.f;
#pragma unroll
    for (int j = 0; j < K; j++) {
        float acc = 0.f;
#pragma unroll
        for (int i = 0; i < K; i++) acc += b[i] * psi[i * K + j];
        o[j] = fmaxf(acc, EPSF);
        sum += o[j];
    }
    float inv = __fdividef(1.f, fmaxf(sum, EPSF));
#pragma unroll
    for (int j = 0; j < K; j++) m[j] = o[j] * inv;
}

__device__ __forceinline__ void acc_log_msg(const float* b, const float* psi, float* acc) {
    float m[K];
    bp_lin(b, psi, m);
#pragma unroll
    for (int j = 0; j < K; j++) acc[j] += __logf(m[j]);
}

// PD record: 16 B = {bf16 prior[7], u15 deg, u1 uniform-m1 flag}
__device__ __forceinline__ void dec_pd(uint4 w, float* p, int* degv, int* u1) {
    p[0] = __uint_as_float((w.x & 0xffffu) << 16);
    p[1] = __uint_as_float(w.x & 0xffff0000u);
    p[2] = __uint_as_float((w.y & 0xffffu) << 16);
    p[3] = __uint_as_float(w.y & 0xffff0000u);
    p[4] = __uint_as_float((w.z & 0xffffu) << 16);
    p[5] = __uint_as_float(w.z & 0xffff0000u);
    p[6] = __uint_as_float((w.w & 0xffffu) << 16);
    *degv = (int)((w.w >> 16) & 0x7fffu);
    *u1 = (int)(w.w >> 31);
}

__device__ __forceinline__ unsigned short f2h(float f) {
    __half h = __float2half_rn(f);
    return *reinterpret_cast<unsigned short*>(&h);
}
__device__ __forceinline__ float h2f(unsigned short u) {
    __half h;
    *reinterpret_cast<unsigned short*>(&h) = u;
    return __half2float(h);
}
// record: 7 fp16 mantissas + shared int16 exponent: value_i = m_i * 2^E
__device__ __forceinline__ uint4 pack7h(const float* m, int E) {
    uint4 r;
    r.x = (unsigned)f2h(m[0]) | ((unsigned)f2h(m[1]) << 16);
    r.y = (unsigned)f2h(m[2]) | ((unsigned)f2h(m[3]) << 16);
    r.z = (unsigned)f2h(m[4]) | ((unsigned)f2h(m[5]) << 16);
    r.w = (unsigned)f2h(m[6]) | ((unsigned)(E & 0xffff) << 16);
    return r;
}
__device__ __forceinline__ int unpack7h(uint4 w, float* m) {
    m[0] = h2f((unsigned short)(w.x & 0xffffu));
    m[1] = h2f((unsigned short)(w.x >> 16));
    m[2] = h2f((unsigned short)(w.y & 0xffffu));
    m[3] = h2f((unsigned short)(w.y >> 16));
    m[4] = h2f((unsigned short)(w.z & 0xffffu));
    m[5] = h2f((unsigned short)(w.z >> 16));
    m[6] = h2f((unsigned short)(w.w & 0xffffu));
    return (int)(short)(w.w >> 16);
}
__device__ __forceinline__ signed char clampE(int E) {
    return (signed char)(E < -120 ? -120 : (E > 120 ? 120 : E));
}

// sniff: dtype + psi structure; also zeros btot (fused memset)
__global__ void sniff11_kernel(const void* __restrict__ W, int* __restrict__ prm,
                               int* __restrict__ btot, int NSB) {
    if (blockIdx.x != 0) return;
    for (int i = threadIdx.x; i < NSB; i += 64) btot[i] = 0;
    if (threadIdx.x != 0) return;
    const unsigned int* Wraw = (const unsigned int*)W;
    int mode = ((Wraw[0] >> 16) != 0u) ? 1 : 0;
    float diag0 = 0.f, offd0 = 0.f;
    int structured = 1;
    for (int i = 0; i < K; i++)
        for (int j = 0; j < K; j++) {
            float w = ldf(W, i * K + j, mode);
            w = fminf(fmaxf(w, -10.f), 10.f);
            float e = __expf(w);
            if (i == 0 && j == 0) diag0 = e;
            if (i == 0 && j == 1) offd0 = e;
            if (i == j) { if (i > 0 && e != diag0) structured = 0; }
            else       { if (!(i == 0 && j == 1) && e != offd0) structured = 0; }
        }
    if (!(offd0 >= 0.2f) || !(diag0 >= offd0)) structured = 0;
    prm[0] = mode | (structured << 1);
    ((float*)prm)[1] = offd0;
    ((float*)prm)[2] = diag0;
}

// ===================== radix-partition CSR build (proven) =====================
__global__ void hist6_kernel(const int* __restrict__ dst, int* __restrict__ hist,
                             int* __restrict__ btot, int E, int EPB, int NSB) {
    __shared__ int h[NSBMAX];
    for (int i = threadIdx.x; i < NSB; i += 256) h[i] = 0;
    __syncthreads();
    int blk = blockIdx.x;
    int e0 = blk * EPB, e1 = min(e0 + EPB, E);
    for (int e = e0 + (int)threadIdx.x; e < e1; e += 256)
        atomicAdd(&h[dst[e] >> SBSH], 1);
    __syncthreads();
    for (int i = threadIdx.x; i < NSB; i += 256) {
        int c = h[i];
        hist[i * PB + blk] = c;
        if (c) atomicAdd(&btot[i], c);
    }
}

__global__ void bscan6_kernel(const int* __restrict__ btot, int* __restrict__ boff, int NSB) {
    __shared__ int s[1024];
    int t = threadIdx.x;
    int x = (t < NSB) ? btot[t] : 0;
    s[t] = x;
    __syncthreads();
    for (int o = 1; o < 1024; o <<= 1) {
        int y = (t >= o) ? s[t - o] : 0;
        __syncthreads();
        s[t] += y;
        __syncthreads();
    }
    if (t < NSB) boff[t] = s[t] - x;
    if (t == NSB - 1) boff[NSB] = s[t];
}

__global__ void sscan6_kernel(const int* __restrict__ hist, const int* __restrict__ boff,
                              int* __restrict__ woff) {
    __shared__ int s[PB];
    int b = blockIdx.x, t = threadIdx.x;
    int x = hist[b * PB + t];
    s[t] = x;
    __syncthreads();
    for (int o = 1; o < PB; o <<= 1) {
        int y = (t >= o) ? s[t - o] : 0;
        __syncthreads();
        s[t] += y;
        __syncthreads();
    }
    woff[b * PB + t] = boff[b] + s[t] - x;
}

__global__ void part6_kernel(const int* __restrict__ src, const int* __restrict__ dst,
                             const int* __restrict__ woff, unsigned int* __restrict__ coarse,
                             int E, int EPB, int NSB) {
    __shared__ int cur[NSBMAX];
    int blk = blockIdx.x;
    for (int i = threadIdx.x; i < NSB; i += 256) cur[i] = woff[i * PB + blk];
    __syncthreads();
    int e0 = blk * EPB, e1 = min(e0 + EPB, E);
    for (int e = e0 + (int)threadIdx.x; e < e1; e += 256) {
        int d = dst[e];
        int b = d >> SBSH;
        unsigned int pk = (unsigned int)src[e] | ((unsigned int)(d & (SBN - 1)) << 18);
        int pos = atomicAdd(&cur[b], 1);
        coarse[pos] = pk;
    }
}

// cfill + fused PD + M1h build (PD/M1h in their OWN buffers — not aliased with coarse)
__global__ void cfill13_kernel(const unsigned int* __restrict__ coarse,
                               const int* __restrict__ boff,
                               const void* __restrict__ prior, const void* __restrict__ W,
                               const int* __restrict__ prm,
                               int* __restrict__ cur, int* __restrict__ nbr,
                               uint4* __restrict__ PD, uint4* __restrict__ M1h, int n) {
    __shared__ int lcnt[SBN], lcur[SBN];
    __shared__ float psi[K * K];
    int b = blockIdx.x, t = threadIdx.x;
    int pm = prm[0];
    int mode = pm & 1, strq = (pm >> 1) & 1;
    float offd = ((const float*)prm)[1], diag = ((const float*)prm)[2];
    load_psi(W, psi, mode);
    for (int i = t; i < SBN; i += 256) lcnt[i] = 0;
    __syncthreads();
    int s0 = boff[b], s1 = boff[b + 1];
    for (int i = s0 + t; i < s1; i += 256)
        atomicAdd(&lcnt[coarse[i] >> 18], 1);
    __syncthreads();
    if (t == 0) {
        int a = s0;
        for (int l = 0; l < SBN; l++) { lcur[l] = a; a += lcnt[l]; }
    }
    __syncthreads();
    int v0 = b << SBSH;
    for (int i = t; i < SBN; i += 256) {
        int v = v0 + i;
        if (v >= n) continue;
        int degv = lcnt[i];
        cur[v] = lcur[i] + degv;
        unsigned int pb[K];
        float p[K];
        if (mode == 0) {
            const unsigned short* pr = (const unsigned short*)prior;
#pragma unroll
            for (int j = 0; j < K; j++) {
                pb[j] = pr[(size_t)v * K + j];
                p[j] = __uint_as_float(pb[j] << 16);
            }
        } else {
            const float* pr = (const float*)prior;
#pragma unroll
            for (int j = 0; j < K; j++) {
                p[j] = pr[(size_t)v * K + j];
                __hip_bfloat16 hh = __float2bfloat16(p[j]);
                pb[j] = *(unsigned short*)&hh;
            }
        }
        float es = __expf((float)(degv - 1) * LOG_INV_K);
        float mx = p[0];
#pragma unroll
        for (int j = 1; j < K; j++) mx = fmaxf(mx, p[j]);
        unsigned int u1 = (mx * es <= EPSF) ? 1u : 0u;
        int dcap = degv > 0x7fff ? 0x7fff : degv;
        uint4 w;
        w.x = pb[0] | (pb[1] << 16);
        w.y = pb[2] | (pb[3] << 16);
        w.z = pb[4] | (pb[5] << 16);
        w.w = pb[6] | (((unsigned int)dcap) << 16) | (u1 << 31);
        PD[v] = w;
        // fused M1h: 7*m1(v); u1 nodes -> exactly 1.0 each
        float bb[K], S = 0.f;
#pragma unroll
        for (int j = 0; j < K; j++) { bb[j] = fmaxf(p[j] * es, EPSF); S += bb[j]; }
        float m1n[K];
        if (strq) {
            float cb = diag - offd, norm = 6.f * offd + diag;
            float sc = __fdividef(7.f, S * norm);
#pragma unroll
            for (int j = 0; j < K; j++) m1n[j] = (offd * S + cb * bb[j]) * sc;
        } else {
            float m1[K];
            bp_lin(bb, psi, m1);
#pragma unroll
            for (int j = 0; j < K; j++) m1n[j] = 7.f * m1[j];
        }
        M1h[v] = pack7h(m1n, 0);
    }
    __syncthreads();
    for (int i = s0 + t; i < s1; i += 256) {
        unsigned int w = coarse[i];
        int pos = atomicAdd(&lcur[w >> 18], 1);
        nbr[pos] = (int)(w & 0x3FFFFu);
    }
}

// ===================== node passes (4 threads/node; live-edge compaction) ==========
__global__ void n2v12_kernel(const int* __restrict__ cur, const int* __restrict__ nbr,
                             const uint4* __restrict__ M1h, const uint4* __restrict__ PD,
                             const int* __restrict__ prm, uint4* __restrict__ LP1,
                             signed char* __restrict__ E1x, int n) {
    int t = blockIdx.x * blockDim.x + threadIdx.x;
    int v = t >> 2, qi = t & 3;
    if (v >= n) return;
    int start = v ? cur[v - 1] : 0, end = cur[v];
    int len = end - start;
    int lo = start + ((len * qi) >> 2), hi = start + ((len * (qi + 1)) >> 2);
    float acc[K] = {1.f, 1.f, 1.f, 1.f, 1.f, 1.f, 1.f};
    int e = lo;
    for (; e + 3 < hi; e += 4) {
        int u0 = nbr[e], u1 = nbr[e + 1], u2 = nbr[e + 2], u3 = nbr[e + 3];
        uint4 w0 = M1h[u0], w1 = M1h[u1], w2 = M1h[u2], w3 = M1h[u3];
        float a[K], b[K], c[K], d[K];
        unpack7h(w0, a); unpack7h(w1, b); unpack7h(w2, c); unpack7h(w3, d);
#pragma unroll
        for (int i = 0; i < K; i++) acc[i] *= (a[i] * b[i]) * (c[i] * d[i]);
    }
    for (; e < hi; e++) {
        float a[K];
        unpack7h(M1h[nbr[e]], a);
#pragma unroll
        for (int i = 0; i < K; i++) acc[i] *= fmaxf(a[i], 1e-30f);
    }
#pragma unroll
    for (int i = 0; i < K; i++) {
        acc[i] *= __shfl_xor(acc[i], 1, 64);
        acc[i] *= __shfl_xor(acc[i], 2, 64);
    }
    if (qi) return;
    float pv[K]; int dv, u1v;
    dec_pd(PD[v], pv, &dv, &u1v);
    float le[K], mx = -1e30f;
    float corr = (float)len * LOG7;
#pragma unroll
    for (int i = 0; i < K; i++) {
        le[i] = __logf(fmaxf(pv[i] * acc[i], 1e-37f)) - corr;
        mx = fmaxf(mx, le[i]);
    }
    int E1 = (int)ceilf(mx * INV_LN2);
    float fm[K];
#pragma unroll
    for (int i = 0; i < K; i++) fm[i] = __expf(le[i] - (float)E1 * LN2);
    LP1[v] = pack7h(fm, E1);
    E1x[v] = clampE(E1);
}

__global__ void n3v13_kernel(const int* __restrict__ cur, const int* __restrict__ nbr,
                             const uint4* __restrict__ PD, const uint4* __restrict__ LP1,
                             const signed char* __restrict__ E1x,
                             const void* __restrict__ W, const int* __restrict__ prm,
                             uint4* __restrict__ Q2h, signed char* __restrict__ E2x, int n) {
    __shared__ float psi[K * K];
    __shared__ int lively[256 * CAP];   // indexed [depth*256 + lane] -> conflict-free
    int pm = prm[0];
    int mode = pm & 1, strq = (pm >> 1) & 1;
    float offd = ((const float*)prm)[1], diag = ((const float*)prm)[2];
    load_psi(W, psi, mode);
    int t = blockIdx.x * blockDim.x + threadIdx.x;
    int v = t >> 2, qi = t & 3;
    if (v >= n) return;
    int start = v ? cur[v - 1] : 0, end = cur[v];
    int len = end - start;
    int lo = start + ((len * qi) >> 2), hi = start + ((len * (qi + 1)) >> 2);
    float cb = diag - offd, norm = 6.f * offd + diag;
    float pv[K]; int dv, u1v;
    dec_pd(PD[v], pv, &dv, &u1v);
    float rm1v[K];
    if (strq && u1v) {
#pragma unroll
        for (int i = 0; i < K; i++) rm1v[i] = 7.f;
    } else {
        float es = __expf((float)(dv - 1) * LOG_INV_K);
        float b1[K], S1 = 0.f;
#pragma unroll
        for (int i = 0; i < K; i++) { b1[i] = fmaxf(pv[i] * es, EPSF); S1 += b1[i]; }
        if (strq) {
            float inv = __fdividef(1.f, S1 * norm);
#pragma unroll
            for (int i = 0; i < K; i++)
                rm1v[i] = __fdividef(1.f, (offd * S1 + cb * b1[i]) * inv);
        } else {
            float m1[K];
            bp_lin(b1, psi, m1);
#pragma unroll
            for (int i = 0; i < K; i++) rm1v[i] = __fdividef(1.f, m1[i]);
        }
    }
    float acc[K];
    int cn = 0;
    if (strq) {
        float F = __fdividef(norm, offd) * 1.01f;
        int Ethr = (int)floorf(LOG2_EPS - log2f(F));
#pragma unroll
        for (int i = 0; i < K; i++) acc[i] = 1.f;
        auto proc = [&](uint4 q) {
            float m[K];
            int E = unpack7h(q, m);
            float b[K], S = 0.f;
#pragma unroll
            for (int i = 0; i < K; i++) {
                b[i] = fmaxf(ldexpf(m[i] * rm1v[i], E), EPSF);
                S += b[i];
            }
            float crS = __fdividef(cb, S);
#pragma unroll
            for (int i = 0; i < K; i++) acc[i] *= fmaf(crS, b[i], offd);
            cn++;
        };
        int lane = (int)threadIdx.x;
        int cnt = 0;
        auto consider = [&](int u, int Eu) {
            if (Eu > Ethr) {
                if (cnt < CAP) lively[cnt++ * 256 + lane] = u;
                else proc(LP1[u]);
            }
        };
        int e = lo;
        for (; e + 3 < hi; e += 4) {
            int u0 = nbr[e], u1 = nbr[e + 1], u2 = nbr[e + 2], u3 = nbr[e + 3];
            int a0 = E1x[u0], a1 = E1x[u1], a2 = E1x[u2], a3 = E1x[u3];
            consider(u0, a0); consider(u1, a1); consider(u2, a2); consider(u3, a3);
        }
        for (; e < hi; e++) { int u = nbr[e]; consider(u, (int)E1x[u]); }
        for (int j = 0; j < cnt; j++) proc(LP1[lively[j * 256 + lane]]);
#pragma unroll
        for (int i = 0; i < K; i++) {
            acc[i] *= __shfl_xor(acc[i], 1, 64);
            acc[i] *= __shfl_xor(acc[i], 2, 64);
        }
    } else {
#pragma unroll
        for (int i = 0; i < K; i++) acc[i] = 0.f;
        for (int e = lo; e < hi; e++) {
            float m[K];
            int E = unpack7h(LP1[nbr[e]], m);
            float b[K];
#pragma unroll
            for (int i = 0; i < K; i++)
                b[i] = fmaxf(ldexpf(m[i] * rm1v[i], E), EPSF);
            acc_log_msg(b, psi, acc);
        }
#pragma unroll
        for (int i = 0; i < K; i++) {
            acc[i] += __shfl_xor(acc[i], 1, 64);
            acc[i] += __shfl_xor(acc[i], 2, 64);
        }
    }
    cn += __shfl_xor(cn, 1, 64);
    cn += __shfl_xor(cn, 2, 64);
    if (qi) return;
    float le2[K], mx = -1e30f;
    if (strq) {
        float corr = (float)cn * __logf(norm) + (float)(len - cn) * LOG7;
#pragma unroll
        for (int i = 0; i < K; i++) {
            le2[i] = __logf(fmaxf(pv[i] * acc[i], 1e-37f)) - corr;
            mx = fmaxf(mx, le2[i]);
        }
    } else {
#pragma unroll
        for (int i = 0; i < K; i++) {
            le2[i] = __logf(fmaxf(pv[i], 1e-37f)) + acc[i];
            mx = fmaxf(mx, le2[i]);
        }
    }
    int E2 = (int)ceilf(mx * INV_LN2);
    float fm[K];
#pragma unroll
    for (int i = 0; i < K; i++) fm[i] = __expf(le2[i] - (float)E2 * LN2);
    Q2h[v] = pack7h(fm, E2);
    E2x[v] = clampE(E2);
}

__global__ void n4v13_kernel(const int* __restrict__ cur, const int* __restrict__ nbr,
                             const uint4* __restrict__ M1h, const uint4* __restrict__ Q2h,
                             const signed char* __restrict__ E2x,
                             const uint4* __restrict__ LP1, const void* __restrict__ prior,
                             const void* __restrict__ W, const int* __restrict__ prm,
                             void* __restrict__ out, int n) {
    __shared__ float psi[K * K];
    __shared__ int lively[256 * CAP];
    int pm = prm[0];
    int mode = pm & 1, strq = (pm >> 1) & 1;
    float offd = ((const float*)prm)[1], diag = ((const float*)prm)[2];
    load_psi(W, psi, mode);
    int t = blockIdx.x * blockDim.x + threadIdx.x;
    int v = t >> 2, qi = t & 3;
    if (v >= n) return;
    int start = v ? cur[v - 1] : 0, end = cur[v];
    int len = end - start;
    int lo = start + ((len * qi) >> 2), hi = start + ((len * (qi + 1)) >> 2);
    float cb = diag - offd, norm = 6.f * offd + diag;
    float e1v[K];
    {
        float m[K];
        int E1 = unpack7h(LP1[v], m);
#pragma unroll
        for (int i = 0; i < K; i++) e1v[i] = ldexpf(m[i], E1);
    }
    float acc[K];
    int cn = 0;
    if (strq) {
        float mx1 = e1v[0];
#pragma unroll
        for (int i = 1; i < K; i++) mx1 = fmaxf(mx1, e1v[i]);
        float F = __fdividef(norm, offd) * 1.01f;
        int m2u = (F * mx1 <= EPSF);
        int Ethr = (int)floorf(LOG2_EPS - log2f(F));
#pragma unroll
        for (int i = 0; i < K; i++) acc[i] = 1.f;
        auto proc2u = [&](int u) {
            float m[K];
            int E2 = unpack7h(Q2h[u], m);
            float b3[K], S = 0.f;
#pragma unroll
            for (int i = 0; i < K; i++) {
                b3[i] = fmaxf(ldexpf(m[i] * 7.f, E2), EPSF);
                S += b3[i];
            }
            float crS = __fdividef(cb, S);
#pragma unroll
            for (int i = 0; i < K; i++) acc[i] *= fmaf(crS, b3[i], offd);
            cn++;
        };
        auto procGen = [&](int u) {
            float m[K];
            int E2 = unpack7h(Q2h[u], m);
            float tt[K];
            unpack7h(M1h[u], tt);
            float b2[K], S2 = 0.f;
#pragma unroll
            for (int i = 0; i < K; i++) {
                b2[i] = fmaxf(e1v[i] * __fdividef(7.f, tt[i]), EPSF);
                S2 += b2[i];
            }
            float inv2 = __fdividef(1.f, S2 * norm);
            float b3[K], S3 = 0.f;
#pragma unroll
            for (int i = 0; i < K; i++) {
                float m2v = (offd * S2 + cb * b2[i]) * inv2;
                float e2 = ldexpf(m[i], E2);
                b3[i] = fmaxf(__fdividef(e2, m2v), EPSF);
                S3 += b3[i];
            }
            float crS3 = __fdividef(cb, S3);
#pragma unroll
            for (int i = 0; i < K; i++) acc[i] *= fmaf(crS3, b3[i], offd);
            cn++;
        };
        int lane = (int)threadIdx.x;
        int cnt = 0;
        auto consider = [&](int u, int Eu) {
            if (Eu > Ethr) {
                if (cnt < CAP) lively[cnt++ * 256 + lane] = u;
                else { if (m2u) proc2u(u); else procGen(u); }
            }
        };
        int e = lo;
        for (; e + 3 < hi; e += 4) {
            int u0 = nbr[e], u1 = nbr[e + 1], u2 = nbr[e + 2], u3 = nbr[e + 3];
            int a0 = E2x[u0], a1 = E2x[u1], a2 = E2x[u2], a3 = E2x[u3];
            consider(u0, a0); consider(u1, a1); consider(u2, a2); consider(u3, a3);
        }
        for (; e < hi; e++) { int u = nbr[e]; consider(u, (int)E2x[u]); }
        if (m2u) { for (int j = 0; j < cnt; j++) proc2u(lively[j * 256 + lane]); }
        else     { for (int j = 0; j < cnt; j++) procGen(lively[j * 256 + lane]); }
#pragma unroll
        for (int i = 0; i < K; i++) {
            acc[i] *= __shfl_xor(acc[i], 1, 64);
            acc[i] *= __shfl_xor(acc[i], 2, 64);
        }
    } else {
#pragma unroll
        for (int i = 0; i < K; i++) acc[i] = 0.f;
        for (int e = lo; e < hi; e++) {
            int u = nbr[e];
            uint4 q = Q2h[u];
            float m[K];
            int E2 = unpack7h(q, m);
            float tt[K];
            unpack7h(M1h[u], tt);
            float b2[K];
#pragma unroll
            for (int i = 0; i < K; i++)
                b2[i] = fmaxf(e1v[i] * __fdividef(7.f, fmaxf(tt[i], 1e-30f)), EPSF);
            float m2[K];
            bp_lin(b2, psi, m2);
            float b3[K];
#pragma unroll
            for (int i = 0; i < K; i++) {
                float e2 = ldexpf(m[i], E2);
                b3[i] = fmaxf(__fdividef(e2, m2[i]), EPSF);
            }
            acc_log_msg(b3, psi, acc);
        }
#pragma unroll
        for (int i = 0; i < K; i++) {
            acc[i] += __shfl_xor(acc[i], 1, 64);
            acc[i] += __shfl_xor(acc[i], 2, 64);
        }
    }
    cn += __shfl_xor(cn, 1, 64);
    cn += __shfl_xor(cn, 2, 64);
    if (qi) return;
    float bb[K], sum = 0.f;
    if (strq) {
        float corr = (float)cn * __logf(norm) + (float)(len - cn) * LOG7;
#pragma unroll
        for (int i = 0; i < K; i++) {
            float p = ldf(prior, (size_t)v * K + i, mode);
            bb[i] = fmaxf(__expf(__logf(fmaxf(p * acc[i], 1e-37f)) - corr), EPSF);
            sum += bb[i];
        }
    } else {
#pragma unroll
        for (int i = 0; i < K; i++) {
            float p = ldf(prior, (size_t)v * K + i, mode);
            bb[i] = fmaxf(p * __expf(acc[i]), EPSF);
            sum += bb[i];
        }
    }
    float inv = __fdividef(1.f, fmaxf(sum, EPSF));
#pragma unroll
    for (int i = 0; i < K; i++) {
        float val = bb[i] * inv;
        if (mode) ((float*)out)[(size_t)v * K + i] = val;
        else ((__hip_bfloat16*)out)[(size_t)v * K + i] = __float2bfloat16(val);
    }
}

// ===================== fallback: round-2 atomic path (proven) =====================
__device__ __forceinline__ void bp_msg(const float* b, const float* psi, float* lm) {
    float m[K];
    bp_lin(b, psi, m);
#pragma unroll
    for (int j = 0; j < K; j++) lm[j] = __logf(m[j]);
}
__device__ __forceinline__ void msg1(const void* prior, int node, int degv, int mode,
                                     const float* psi, float* lm) {
    float es = __expf((float)(degv - 1) * LOG_INV_K);
    float b[K];
#pragma unroll
    for (int i = 0; i < K; i++)
        b[i] = fmaxf(ldf(prior, (size_t)node * K + i, mode) * es, EPSF);
    bp_msg(b, psi, lm);
}
__device__ __forceinline__ void msgF(const void* prior, int node,
                                     const float* __restrict__ logP,
                                     const float* lmrev, int mode,
                                     const float* psi, float* lm) {
    float b[K];
#pragma unroll
    for (int i = 0; i < K; i++)
        b[i] = fmaxf(ldf(prior, (size_t)node * K + i, mode) *
                     __expf(logP[(size_t)node * K + i] - lmrev[i]), EPSF);
    bp_msg(b, psi, lm);
}
__global__ void deg_kernel(const int* __restrict__ su, const int* __restrict__ du,
                           int* __restrict__ deg, int Eu) {
    int u = blockIdx.x * blockDim.x + threadIdx.x;
    if (u >= Eu) return;
    atomicAdd(&deg[su[u]], 1);
    atomicAdd(&deg[du[u]], 1);
}
__global__ void pass1_kernel(const int* __restrict__ su, const int* __restrict__ du,
                             const int* __restrict__ deg, const void* __restrict__ prior,
                             const void* __restrict__ W, const int* __restrict__ prm,
                             float* __restrict__ logP1, int Eu) {
    __shared__ float psi[K * K];
    int mode = prm[0] & 1;
    load_psi(W, psi, mode);
    int u = blockIdx.x * blockDim.x + threadIdx.x;
    if (u >= Eu) return;
    int s = su[u], d = du[u];
    float lm[K];
    msg1(prior, s, deg[s], mode, psi, lm);
#pragma unroll
    for (int j = 0; j < K; j++) atomicAdd(&logP1[(size_t)d * K + j], lm[j]);
    msg1(prior, d, deg[d], mode, psi, lm);
#pragma unroll
    for (int j = 0; j < K; j++) atomicAdd(&logP1[(size_t)s * K + j], lm[j]);
}
__global__ void pass2_kernel(const int* __restrict__ su, const int* __restrict__ du,
                             const int* __restrict__ deg, const void* __restrict__ prior,
                             const void* __restrict__ W, const int* __restrict__ prm,
                             const float* __restrict__ logP1, float* __restrict__ logP2, int Eu) {
    __shared__ float psi[K * K];
    int mode = prm[0] & 1;
    load_psi(W, psi, mode);
    int u = blockIdx.x * blockDim.x + threadIdx.x;
    if (u >= Eu) return;
    int s = su[u], d = du[u];
    float lm1sd[K], lm1ds[K], lm[K];
    msg1(prior, s, deg[s], mode, psi, lm1sd);
    msg1(prior, d, deg[d], mode, psi, lm1ds);
    msgF(prior, s, logP1, lm1ds, mode, psi, lm);
#pragma unroll
    for (int j = 0; j < K; j++) atomicAdd(&logP2[(size_t)d * K + j], lm[j]);
    msgF(prior, d, logP1, lm1sd, mode, psi, lm);
#pragma unroll
    for (int j = 0; j < K; j++) atomicAdd(&logP2[(size_t)s * K + j], lm[j]);
}
__global__ void pass3_kernel(const int* __restrict__ su, const int* __restrict__ du,
                             const int* __restrict__ deg, const void* __restrict__ prior,
                             const void* __restrict__ W, const int* __restrict__ prm,
                             const float* __restrict__ logP1, const float* __restrict__ logP2,
                             float* __restrict__ logP3, int Eu) {
    __shared__ float psi[K * K];
    int mode = prm[0] & 1;
    load_psi(W, psi, mode);
    int u = blockIdx.x * blockDim.x + threadIdx.x;
    if (u >= Eu) return;
    int s = su[u], d = du[u];
    float lm1sd[K], lm1ds[K], lm2sd[K], lm2ds[K], lm[K];
    msg1(prior, s, deg[s], mode, psi, lm1sd);
    msg1(prior, d, deg[d], mode, psi, lm1ds);
    msgF(prior, s, logP1, lm1ds, mode, psi, lm2sd);
    msgF(prior, d, logP1, lm1sd, mode, psi, lm2ds);
    msgF(prior, s, logP2, lm2ds, mode, psi, lm);
#pragma unroll
    for (int j = 0; j < K; j++) atomicAdd(&logP3[(size_t)d * K + j], lm[j]);
    msgF(prior, d, logP2, lm2sd, mode, psi, lm);
#pragma unroll
    for (int j = 0; j < K; j++) atomicAdd(&logP3[(size_t)s * K + j], lm[j]);
}
__global__ void belief_kernel(const float* __restrict__ logP3, const void* __restrict__ prior,
                              const int* __restrict__ prm, void* __restrict__ out, int n) {
    int v = blockIdx.x * blockDim.x + threadIdx.x;
    if (v >= n) return;
    int mode = prm[0] & 1;
    float b[K], sum = 0.f;
#pragma unroll
    for (int j = 0; j < K; j++) {
        b[j] = fmaxf(ldf(prior, (size_t)v * K + j, mode) * __expf(logP3[(size_t)v * K + j]), EPSF);
        sum += b[j];
    }
    float inv = __fdividef(1.f, fmaxf(sum, EPSF));
#pragma unroll
    for (int j = 0; j < K; j++) {
        float val = b[j] * inv;
        if (mode) ((float*)out)[(size_t)v * K + j] = val;
        else ((__hip_bfloat16*)out)[(size_t)v * K + j] = __float2bfloat16(val);
    }
}

extern "C" void kernel_launch(void* const* d_in, const int* in_sizes, int n_in,
                              void* d_out, int out_size, void* d_ws, size_t ws_size,
                              hipStream_t stream) {
    const void* prior = d_in[0];
    const void* W     = d_in[1];
    const int* src = (const int*)d_in[2];
    const int* dst = (const int*)d_in[3];

    int n  = in_sizes[0] / K;
    int E  = in_sizes[2];
    int Eu = E / 2;

    const int B = 256;
    int gn  = (n + B - 1) / B;
    int gn4 = (4 * n + B - 1) / B;
    int ge  = (Eu + B - 1) / B;

    int NSB = (n + SBN - 1) >> SBSH;
    int EPB = (E + PB - 1) / PB;

    char* ws = (char*)d_ws;
    size_t off = 0;
    auto alloc = [&](size_t bytes) { size_t o = off; off = (off + bytes + 127) & ~(size_t)127; return o; };

    // v13 layout: nbr | X (coarse E*4; after build: LP1@0, Q2h@n*16) | PD n*16 |
    //             M1h n*16 | E1x n | E2x n | cur | hist | woff | boff | btot | prm
    size_t xsz = (size_t)E * 4;
    if ((size_t)n * 32 > xsz) xsz = (size_t)n * 32;
    size_t o_nbr  = alloc((size_t)E * 4);
    size_t o_X    = alloc(xsz);
    size_t o_PD   = alloc((size_t)n * 16);
    size_t o_M1h  = alloc((size_t)n * 16);
    size_t o_E1x  = alloc((size_t)n);
    size_t o_E2x  = alloc((size_t)n);
    size_t o_cur  = alloc((size_t)n * 4);
    size_t o_hist = alloc((size_t)NSB * PB * 4);
    size_t o_woff = alloc((size_t)NSB * PB * 4);
    size_t o_boff = alloc((size_t)(NSB + 1) * 4);
    size_t o_btot = alloc((size_t)NSB * 4);
    size_t o_prm  = alloc(64);
    size_t need_v13 = off;

    bool v13_ok = (ws_size >= need_v13) && (n <= (1 << 18)) && (NSB <= NSBMAX) && (NSB >= 1);

    if (v13_ok) {
        int*   nbr    = (int*)(ws + o_nbr);
        unsigned int* coarse = (unsigned int*)(ws + o_X);   // dead after cfill13
        uint4* LP1    = (uint4*)(ws + o_X);                 // X reuse after build
        uint4* Q2h    = (uint4*)(ws + o_X + (size_t)n * 16);
        uint4* PD     = (uint4*)(ws + o_PD);
        uint4* M1h    = (uint4*)(ws + o_M1h);
        signed char* E1x = (signed char*)(ws + o_E1x);
        signed char* E2x = (signed char*)(ws + o_E2x);
        int*   cur    = (int*)(ws + o_cur);
        int*   hist   = (int*)(ws + o_hist);
        int*   woff   = (int*)(ws + o_woff);
        int*   boff   = (int*)(ws + o_boff);
        int*   btot   = (int*)(ws + o_btot);
        int*   prm    = (int*)(ws + o_prm);

        sniff11_kernel<<<1, 64, 0, stream>>>(W, prm, btot, NSB);
        hist6_kernel<<<PB, B, 0, stream>>>(dst, hist, btot, E, EPB, NSB);
        bscan6_kernel<<<1, 1024, 0, stream>>>(btot, boff, NSB);
        sscan6_kernel<<<NSB, PB, 0, stream>>>(hist, boff, woff);
        part6_kernel<<<PB, B, 0, stream>>>(src, dst, woff, coarse, E, EPB, NSB);
        cfill13_kernel<<<NSB, B, 0, stream>>>(coarse, boff, prior, W, prm, cur, nbr,
                                              PD, M1h, n);
        n2v12_kernel<<<gn4, B, 0, stream>>>(cur, nbr, M1h, PD, prm, LP1, E1x, n);
        n3v13_kernel<<<gn4, B, 0, stream>>>(cur, nbr, PD, LP1, E1x, W, prm, Q2h, E2x, n);
        n4v13_kernel<<<gn4, B, 0, stream>>>(cur, nbr, M1h, Q2h, E2x, LP1, prior, W, prm,
                                            d_out, n);
        return;
    }

    // fallback: round-2 atomic path (17.6 MB)
    {
        float* logP1 = (float*)d_ws;
        float* logP2 = logP1 + (size_t)n * K;
        float* logP3 = logP2 + (size_t)n * K;
        int*   deg   = (int*)(logP3 + (size_t)n * K);
        int*   prm   = deg + n;
        int*   btot  = prm + 8;
        sniff11_kernel<<<1, 64, 0, stream>>>(W, prm, btot, 0);
        hipMemsetAsync(d_ws, 0, ((size_t)3 * n * K + n) * sizeof(float), stream);
        deg_kernel<<<ge, B, 0, stream>>>(src, dst, deg, Eu);
        pass1_kernel<<<ge, B, 0, stream>>>(src, dst, deg, prior, W, prm, logP1, Eu);
        pass2_kernel<<<ge, B, 0, stream>>>(src, dst, deg, prior, W, prm, logP1, logP2, Eu);
        pass3_kernel<<<ge, B, 0, stream>>>(src, dst, deg, prior, W, prm, logP1, logP2, logP3, Eu);
        belief_kernel<<<gn, B, 0, stream>>>(logP3, prior, prm, d_out, n);
    }
}